// Round 11
// baseline (1476.771 us; speedup 1.0000x reference)
//
#include <hip/hip_runtime.h>

// Fused flash-style softmax(Q V^T) V, B=4, NQ=NK=4096, D=1024, fp32 in/out.
// Round 11: delete the LDS V tile. PV B-frags (V^T, k-contraction) are loaded
// DIRECTLY from global V with a fully-coalesced per-(dg,j) dword pattern
// (L2-resident re-read; XCD swizzle groups same-batch blocks per XCD).
// QK^T keeps register-staged V (hA/hB). LDS = spart + pbuf only (~35 KB);
// block LDS ops drop 83 -> 15 per wave/tile (the r9 bottleneck).
// Softmax: defer-max (THR=8, running max in regs), lane-local l accumulation
// (single epilogue reduction), conditional O rescale. All plain VALU logic.
// NO inline-asm loads, NO tr_b16, NO DPP (all banned: 3 silicon failures).

#define NB   4
#define NQL  4096
#define NKL  4096
#define DIM  1024
#define BQ   32
#define BK   32
#define NW   8
#define DSL  128
#define NT   (NKL / BK)
#define LOG2E 1.44269504088896340736f
#define PBW  40            // pbuf row stride in shorts (80 B)

typedef float f32x2 __attribute__((ext_vector_type(2)));
typedef float f32x4 __attribute__((ext_vector_type(4)));
typedef _Float16 f16x8 __attribute__((ext_vector_type(8)));
typedef short s16x8 __attribute__((ext_vector_type(8)));
typedef unsigned int uint_;

union Frag { f16x8 v; s16x8 s; _Float16 h[8]; };

__device__ __forceinline__ void rawbar() {  // LDS visibility only; vmem stays in flight
    asm volatile("s_waitcnt lgkmcnt(0)\n\ts_barrier" ::: "memory");
}

__global__ __attribute__((amdgpu_flat_work_group_size(512, 512),
                          amdgpu_waves_per_eu(2, 2)))
void attn_f16(const float* __restrict__ Qg, const float* __restrict__ Vg,
              float* __restrict__ Og) {
    __shared__ float spart[NW][BQ][BK];                   // 32 KB (swizzled k idx)
    __shared__ __align__(16) short pbuf[BQ * PBW];        // 2.5 KB (fp16 P)
    __shared__ float arun[BQ];                            // per-q alpha of this tile
    __shared__ float lsum[BQ];                            // epilogue l reduction

    const int tid = (int)threadIdx.x;
    const int l   = tid & 63;
    const int w   = tid >> 6;
    const int l15 = l & 15;
    const int lg  = l >> 4;

    // XCD-aware swizzle (512 blocks, 8 XCDs, 512%8==0 -> bijective):
    // XCD x gets original ids [x*64, x*64+64) -> same batch b, contiguous qt.
    const int bid  = (int)blockIdx.x;
    const int orig = (bid & 7) * 64 + (bid >> 3);
    const int b  = orig >> 7;
    const int qt = orig & 127;
    const int q0 = qt * BQ;
    const int dw = w * DSL;

    // Q fragments (B-operand): lane holds Q[q0+qb*16+l15][dw+dc*32+lg*8 .. +7] fp16
    f16x8 qf[2][4];
#pragma unroll
    for (int qb = 0; qb < 2; ++qb)
#pragma unroll
        for (int dc = 0; dc < 4; ++dc) {
            const float* qp = Qg + (size_t)(b * NQL + q0 + qb * 16 + l15) * DIM
                            + dw + dc * 32 + lg * 8;
            f32x4 x0 = *(const f32x4*)qp;
            f32x4 x1 = *(const f32x4*)(qp + 4);
            f16x8 a;
#pragma unroll
            for (int j = 0; j < 4; ++j) { a[j] = (_Float16)x0[j]; a[j + 4] = (_Float16)x1[j]; }
            qf[qb][dc] = a;
        }

    f32x4 oacc[2][8];
#pragma unroll
    for (int qb = 0; qb < 2; ++qb)
#pragma unroll
        for (int dg = 0; dg < 8; ++dg)
            oacc[qb][dg] = (f32x4){0.f, 0.f, 0.f, 0.f};

    f32x4 sacc[2][2];
    f32x4 hA[4][2], hB[4][2];  // QK^T staging buffers (32 VGPR each)

    auto loadhalf = [&](f32x4 (&buf)[4][2], int kt_, int kb) {
        const float* vp = Vg + (size_t)(b * NKL + kt_ * BK + kb * 16 + l15) * DIM
                        + dw + lg * 8;
#pragma unroll
        for (int dc = 0; dc < 4; ++dc) {
            buf[dc][0] = *(const f32x4*)(vp + dc * 32);
            buf[dc][1] = *(const f32x4*)(vp + dc * 32 + 4);
        }
    };

    auto computehalf = [&](f32x4 (&buf)[4][2], int kb) {
#pragma unroll
        for (int dc = 0; dc < 4; ++dc) {
            Frag fa;
#pragma unroll
            for (int j = 0; j < 4; ++j) {
                fa.h[j]     = (_Float16)buf[dc][0][j];
                fa.h[j + 4] = (_Float16)buf[dc][1][j];
            }
            sacc[kb][0] = __builtin_amdgcn_mfma_f32_16x16x32_f16(fa.v, qf[0][dc], sacc[kb][0], 0, 0, 0);
            sacc[kb][1] = __builtin_amdgcn_mfma_f32_16x16x32_f16(fa.v, qf[1][dc], sacc[kb][1], 0, 0, 0);
        }
    };

    // softmax assignment: lane handles q = 4w+lg, k-pair {2*l15, 2*l15+1}
    const int qsm = 4 * w + lg;
    const int kk  = (2 * l15) ^ ((qsm & 7) << 2);   // swizzled read offset (even)

    float m_reg  = -3e38f;   // running max (16-lane-group uniform)
    float l_lane = 0.f;      // lane-local denominator partial

    loadhalf(hA, 0, 0);
    loadhalf(hB, 0, 1);
    rawbar();

    for (int kt = 0; kt < NT; ++kt) {
#pragma unroll
        for (int kb = 0; kb < 2; ++kb)
#pragma unroll
            for (int qb = 0; qb < 2; ++qb)
                sacc[kb][qb] = (f32x4){0.f, 0.f, 0.f, 0.f};

        const int ktn = (kt + 1 < NT) ? kt + 1 : NT - 1;
        computehalf(hA, 0);
        loadhalf(hA, ktn, 0);   // next tile QK^T staging, in flight across B1/B2
        computehalf(hB, 1);
        loadhalf(hB, ktn, 1);

        // S^T partials -> spart, b128 stores at XOR-swizzled k-block
#pragma unroll
        for (int kb = 0; kb < 2; ++kb)
#pragma unroll
            for (int qb = 0; qb < 2; ++qb) {
                const int q = qb * 16 + l15;
                const int kblk = (kb * 16 + lg * 4) ^ ((q & 7) << 2);
                *(f32x4*)&spart[w][q][kblk] = sacc[kb][qb];
            }
        rawbar();  // B1

        // PV V^T loads for THIS tile, direct from global (L2-resident re-read).
        // Issued here so softmax covers their latency; uses are after B2.
        // pv[dg][j] = V[kbase + lg*8 + j][dw + dg*16 + l15]
        float pv[8][8];
        {
            const float* vb = Vg + (size_t)(b * NKL + kt * BK + lg * 8) * DIM
                            + dw + l15;
#pragma unroll
            for (int dg = 0; dg < 8; ++dg)
#pragma unroll
                for (int j = 0; j < 8; ++j)
                    pv[dg][j] = vb[(size_t)j * DIM + dg * 16];
        }

        // Phase 2: reduce over waves, defer-max online softmax
        {
            f32x2 sp = (f32x2){0.f, 0.f};
#pragma unroll
            for (int wv = 0; wv < NW; ++wv)
                sp += *(const f32x2*)&spart[wv][qsm][kk];
            float s0 = sp[0], s1 = sp[1];   // scores k=2*l15, 2*l15+1
            float smax = fmaxf(s0, s1);
            float alpha = 1.0f;
            if (!__all(smax - m_reg <= 8.0f)) {   // wave-uniform branch
                float mloc = smax;
#pragma unroll
                for (int off = 1; off < 16; off <<= 1)
                    mloc = fmaxf(mloc, __shfl_xor(mloc, off));
                float mnew = fmaxf(m_reg, mloc);
                alpha = exp2f((m_reg - mnew) * LOG2E);
                m_reg = mnew;
            }
            float p0 = exp2f((s0 - m_reg) * LOG2E);
            float p1 = exp2f((s1 - m_reg) * LOG2E);
            l_lane = alpha * l_lane + (p0 + p1);
            if (l15 == 0) arun[qsm] = alpha;
            uint_ pk = (uint_)__builtin_bit_cast(unsigned short, (_Float16)p0)
                     | ((uint_)__builtin_bit_cast(unsigned short, (_Float16)p1) << 16);
            *(uint_*)&pbuf[qsm * PBW + 2 * l15] = pk;
        }
        rawbar();  // B2

        // Phase 3: conditional rescale, then O += P * V
        {
            f32x4 av[2];
#pragma unroll
            for (int qb = 0; qb < 2; ++qb)
                av[qb] = *(const f32x4*)&arun[qb * 16 + lg * 4];
            bool mine1 = true;
#pragma unroll
            for (int qb = 0; qb < 2; ++qb)
#pragma unroll
                for (int r = 0; r < 4; ++r)
                    mine1 = mine1 && (av[qb][r] == 1.0f);
            if (!__all(mine1)) {
#pragma unroll
                for (int qb = 0; qb < 2; ++qb)
#pragma unroll
                    for (int dg = 0; dg < 8; ++dg)
#pragma unroll
                        for (int r = 0; r < 4; ++r)
                            oacc[qb][dg][r] *= av[qb][r];
            }
        }

        Frag pf[2];
#pragma unroll
        for (int qb = 0; qb < 2; ++qb)
            pf[qb].s = *(const s16x8*)&pbuf[(qb * 16 + l15) * PBW + lg * 8];

#pragma unroll
        for (int dg = 0; dg < 8; ++dg) {
            Frag bf;
#pragma unroll
            for (int j = 0; j < 8; ++j)
                bf.h[j] = (_Float16)pv[dg][j];
            __builtin_amdgcn_s_setprio(1);
#pragma unroll
            for (int qb = 0; qb < 2; ++qb)
                oacc[qb][dg] = __builtin_amdgcn_mfma_f32_16x16x32_f16(
                    pf[qb].v, bf.v, oacc[qb][dg], 0, 0, 0);
            __builtin_amdgcn_s_setprio(0);
        }
    }

    // Epilogue: reduce l across the 16-lane group (once), normalize, store.
    {
        float rs = l_lane;
#pragma unroll
        for (int off = 1; off < 16; off <<= 1)
            rs += __shfl_xor(rs, off);
        if (l15 == 0) lsum[qsm] = rs;
    }
    __syncthreads();
#pragma unroll
    for (int qb = 0; qb < 2; ++qb) {
        f32x4 lv = *(const f32x4*)&lsum[qb * 16 + lg * 4];
        float il[4];
#pragma unroll
        for (int r = 0; r < 4; ++r) il[r] = 1.0f / lv[r];
#pragma unroll
        for (int dg = 0; dg < 8; ++dg)
#pragma unroll
            for (int r = 0; r < 4; ++r) {
                int q = q0 + qb * 16 + lg * 4 + r;
                int d = dw + dg * 16 + l15;
                Og[(size_t)(b * NQL + q) * DIM + d] = oacc[qb][dg][r] * il[r];
            }
    }
}

extern "C" void kernel_launch(void* const* d_in, const int* in_sizes, int n_in,
                              void* d_out, int out_size, void* d_ws, size_t ws_size,
                              hipStream_t stream) {
    const float* Q = (const float*)d_in[0];
    const float* V = (const float*)d_in[1];
    float* O = (float*)d_out;
    (void)in_sizes; (void)n_in; (void)out_size; (void)d_ws; (void)ws_size;
    dim3 grid(NB * (NQL / BQ));  // 512 blocks
    dim3 block(NW * 64);         // 512 threads
    attn_f16<<<grid, block, 0, stream>>>(Q, V, O);
}

// Round 12
// 1310.415 us; speedup vs baseline: 1.1269x; 1.1269x over previous
//
#include <hip/hip_runtime.h>

// Fused flash-style softmax(Q V^T) V, B=4, NQ=NK=4096, D=1024, fp32 in/out.
// Round 12: k-sliced restructure. Q lives in LDS (fp16, loaded once); each
// wave owns k-slice [32w,32w+32) of a 256-k tile and computes S^T[32k x 32q]
// with the FULL D=1024 contraction (no cross-wave score reduction, spart
// deleted). Per 256-k tile only 2 barriers (was 16):
//   QK^T (barrier-free) -> wave-local max -> mx exchange -> Ba ->
//   block-uniform m (defer THR=8), P=exp(S-m) -> p_lds, alpha -> Bb ->
//   PV from shared P (wave-private O d-slice, direct-global V^T dwords).
// l is lane-local, one epilogue block reduction. MFMA count unchanged.

#define NB   4
#define NQL  4096
#define NKL  4096
#define DIM  1024
#define BQ   32
#define BKT  256
#define NW   8
#define NT2  (NKL / BKT)   // 16
#define LOG2E 1.44269504088896340736f
#define QLP  1032          // q_lds row stride (shorts): 2064B == 4 dw mod 32 banks
#define PLP  264           // p_lds row stride (shorts): 528B == 4 dw mod 32 banks
#define MXW  12            // mx/lsum row stride (f32): 48B, 16B-aligned rows

typedef float f32x4 __attribute__((ext_vector_type(4)));
typedef _Float16 f16x8 __attribute__((ext_vector_type(8)));
typedef short s16x8 __attribute__((ext_vector_type(8)));
typedef short s16x4 __attribute__((ext_vector_type(4)));

union Frag { f16x8 v; s16x8 s; _Float16 h[8]; };

__device__ __forceinline__ void rawbar() {  // LDS visibility only
    asm volatile("s_waitcnt lgkmcnt(0)\n\ts_barrier" ::: "memory");
}

__global__ __attribute__((amdgpu_flat_work_group_size(512, 512),
                          amdgpu_waves_per_eu(2, 2)))
void attn_f16(const float* __restrict__ Qg, const float* __restrict__ Vg,
              float* __restrict__ Og) {
    __shared__ __align__(16) short q_lds[BQ * QLP];   // 66048 B, fp16 Q tile
    __shared__ __align__(16) short p_lds[BQ * PLP];   // 16896 B, fp16 P tile
    __shared__ __align__(16) float mx[BQ][MXW];       // 1536 B, per-wave tile max
    __shared__ __align__(16) float lsum[BQ][MXW];     // 1536 B, epilogue l
    __shared__ __align__(16) float alr[BQ];           // per-q alpha
    __shared__ __align__(16) float linv[BQ];          // epilogue 1/l

    const int tid = (int)threadIdx.x;
    const int l   = tid & 63;
    const int w   = tid >> 6;
    const int l15 = l & 15;
    const int lg  = l >> 4;

    // XCD-aware swizzle (512 blocks, 8 XCDs, bijective since 512%8==0)
    const int bid  = (int)blockIdx.x;
    const int orig = (bid & 7) * 64 + (bid >> 3);
    const int b  = orig >> 7;
    const int qt = orig & 127;
    const int q0 = qt * BQ;
    const int dw = w * 128;

    // Prologue: Q[q0..q0+32][0..1024) fp32 -> fp16 into q_lds (coalesced flat copy)
    {
        const float* qsrc = Qg + (size_t)(b * NQL + q0) * DIM;
#pragma unroll
        for (int it = 0; it < 16; ++it) {
            const int f = (it * 512 + tid) * 4;      // flat float index
            f32x4 x = *(const f32x4*)(qsrc + f);
            const int row = f >> 10, col = f & 1023;
            s16x4 h;
#pragma unroll
            for (int j = 0; j < 4; ++j)
                h[j] = __builtin_bit_cast(short, (_Float16)x[j]);
            *(s16x4*)&q_lds[row * QLP + col] = h;
        }
    }

    f32x4 oacc[2][8];
#pragma unroll
    for (int qb = 0; qb < 2; ++qb)
#pragma unroll
        for (int dg = 0; dg < 8; ++dg)
            oacc[qb][dg] = (f32x4){0.f, 0.f, 0.f, 0.f};

    float m_reg[2]  = {-3e38f, -3e38f};
    float l_lane[2] = {0.f, 0.f};

    __syncthreads();   // q_lds ready

    for (int kt = 0; kt < NT2; ++kt) {
        // ---- Phase 1: QK^T, full-D contraction, wave k-slice [32w, 32w+32)
        f32x4 sacc[2][2];
#pragma unroll
        for (int kb = 0; kb < 2; ++kb)
#pragma unroll
            for (int qb = 0; qb < 2; ++qb)
                sacc[kb][qb] = (f32x4){0.f, 0.f, 0.f, 0.f};

        const float* vbase = Vg + (size_t)(b * NKL + kt * BKT + w * 32 + l15) * DIM
                           + lg * 8;
#pragma unroll 4
        for (int dc = 0; dc < 32; ++dc) {
            Frag qfr0, qfr1;
            qfr0.s = *(const s16x8*)&q_lds[l15 * QLP + dc * 32 + lg * 8];
            qfr1.s = *(const s16x8*)&q_lds[(16 + l15) * QLP + dc * 32 + lg * 8];
#pragma unroll
            for (int kb = 0; kb < 2; ++kb) {
                const float* vp = vbase + (size_t)(kb * 16) * DIM + dc * 32;
                f32x4 x0 = *(const f32x4*)vp;
                f32x4 x1 = *(const f32x4*)(vp + 4);
                Frag fa;
#pragma unroll
                for (int j = 0; j < 4; ++j) {
                    fa.h[j]     = (_Float16)x0[j];
                    fa.h[j + 4] = (_Float16)x1[j];
                }
                sacc[kb][0] = __builtin_amdgcn_mfma_f32_16x16x32_f16(fa.v, qfr0.v, sacc[kb][0], 0, 0, 0);
                sacc[kb][1] = __builtin_amdgcn_mfma_f32_16x16x32_f16(fa.v, qfr1.v, sacc[kb][1], 0, 0, 0);
            }
        }

        // ---- Phase 2: wave-local per-q max over this wave's 32 k
        float tmax[2];
#pragma unroll
        for (int qb = 0; qb < 2; ++qb) {
            float t = sacc[0][qb][0];
#pragma unroll
            for (int r = 1; r < 4; ++r) t = fmaxf(t, sacc[0][qb][r]);
#pragma unroll
            for (int r = 0; r < 4; ++r) t = fmaxf(t, sacc[1][qb][r]);
            t = fmaxf(t, __shfl_xor(t, 16));
            t = fmaxf(t, __shfl_xor(t, 32));
            tmax[qb] = t;
        }
        if (lg == 0) { mx[l15][w] = tmax[0]; mx[16 + l15][w] = tmax[1]; }
        rawbar();   // Ba

        // ---- Phase 3: block-uniform m (defer THR=8), P, alpha, l
        float alpha[2];
#pragma unroll
        for (int qb = 0; qb < 2; ++qb) {
            const int q = qb * 16 + l15;
            f32x4 ma = *(const f32x4*)&mx[q][0];
            f32x4 mb = *(const f32x4*)&mx[q][4];
            float tm = fmaxf(fmaxf(fmaxf(ma[0], ma[1]), fmaxf(ma[2], ma[3])),
                             fmaxf(fmaxf(mb[0], mb[1]), fmaxf(mb[2], mb[3])));
            const bool defer = (tm - m_reg[qb] <= 8.0f);
            const float mn = fmaxf(m_reg[qb], tm);
            const float mnew = defer ? m_reg[qb] : mn;
            alpha[qb] = defer ? 1.0f : exp2f((m_reg[qb] - mn) * LOG2E);
            m_reg[qb] = mnew;

            float psum = 0.f;
#pragma unroll
            for (int kb = 0; kb < 2; ++kb) {
                s16x4 pk;
#pragma unroll
                for (int r = 0; r < 4; ++r) {
                    float p = exp2f((sacc[kb][qb][r] - mnew) * LOG2E);
                    psum += p;
                    pk[r] = __builtin_bit_cast(short, (_Float16)p);
                }
                *(s16x4*)&p_lds[q * PLP + w * 32 + kb * 16 + lg * 4] = pk;
            }
            l_lane[qb] = alpha[qb] * l_lane[qb] + psum;
        }
        if (lg == 0) { alr[l15] = alpha[0]; alr[16 + l15] = alpha[1]; }
        rawbar();   // Bb

        // ---- Phase 4: conditional rescale, then O += P * V (full 256 k)
        {
            f32x4 av0 = *(const f32x4*)&alr[lg * 4];
            f32x4 av1 = *(const f32x4*)&alr[16 + lg * 4];
            bool one = true;
#pragma unroll
            for (int r = 0; r < 4; ++r)
                one = one && (av0[r] == 1.0f) && (av1[r] == 1.0f);
            if (!__all(one)) {
#pragma unroll
                for (int dg = 0; dg < 8; ++dg)
#pragma unroll
                    for (int r = 0; r < 4; ++r) {
                        oacc[0][dg][r] *= av0[r];
                        oacc[1][dg][r] *= av1[r];
                    }
            }
        }

        const float* vpv = Vg + (size_t)(b * NKL + kt * BKT + lg * 8) * DIM
                         + dw + l15;
#pragma unroll 2
        for (int ks = 0; ks < 8; ++ks) {
            Frag pf0, pf1;
            pf0.s = *(const s16x8*)&p_lds[l15 * PLP + ks * 32 + lg * 8];
            pf1.s = *(const s16x8*)&p_lds[(16 + l15) * PLP + ks * 32 + lg * 8];
            const float* rowp[8];
#pragma unroll
            for (int j = 0; j < 8; ++j)
                rowp[j] = vpv + (size_t)(ks * 32 + j) * DIM;
#pragma unroll
            for (int dg = 0; dg < 8; ++dg) {
                Frag bf;
#pragma unroll
                for (int j = 0; j < 8; ++j)
                    bf.h[j] = (_Float16)rowp[j][dg * 16];
                __builtin_amdgcn_s_setprio(1);
                oacc[0][dg] = __builtin_amdgcn_mfma_f32_16x16x32_f16(pf0.v, bf.v, oacc[0][dg], 0, 0, 0);
                oacc[1][dg] = __builtin_amdgcn_mfma_f32_16x16x32_f16(pf1.v, bf.v, oacc[1][dg], 0, 0, 0);
                __builtin_amdgcn_s_setprio(0);
            }
        }
    }

    // ---- Epilogue: block-reduce l, normalize, store
    {
        float lr0 = l_lane[0], lr1 = l_lane[1];
        lr0 += __shfl_xor(lr0, 16); lr0 += __shfl_xor(lr0, 32);
        lr1 += __shfl_xor(lr1, 16); lr1 += __shfl_xor(lr1, 32);
        if (lg == 0) { lsum[l15][w] = lr0; lsum[16 + l15][w] = lr1; }
    }
    __syncthreads();
    if (tid < BQ) {
        float s = 0.f;
#pragma unroll
        for (int w2 = 0; w2 < 8; ++w2) s += lsum[tid][w2];
        linv[tid] = 1.0f / s;
    }
    __syncthreads();
    {
        f32x4 il0 = *(const f32x4*)&linv[lg * 4];
        f32x4 il1 = *(const f32x4*)&linv[16 + lg * 4];
#pragma unroll
        for (int qb = 0; qb < 2; ++qb)
#pragma unroll
            for (int dg = 0; dg < 8; ++dg)
#pragma unroll
                for (int r = 0; r < 4; ++r) {
                    const int q = q0 + qb * 16 + lg * 4 + r;
                    const int d = dw + dg * 16 + l15;
                    const float sc = (qb == 0) ? il0[r] : il1[r];
                    Og[(size_t)(b * NQL + q) * DIM + d] = oacc[qb][dg][r] * sc;
                }
    }
}

extern "C" void kernel_launch(void* const* d_in, const int* in_sizes, int n_in,
                              void* d_out, int out_size, void* d_ws, size_t ws_size,
                              hipStream_t stream) {
    const float* Q = (const float*)d_in[0];
    const float* V = (const float*)d_in[1];
    float* O = (float*)d_out;
    (void)in_sizes; (void)n_in; (void)out_size; (void)d_ws; (void)ws_size;
    dim3 grid(NB * (NQL / BQ));  // 512 blocks
    dim3 block(NW * 64);         // 512 threads
    attn_f16<<<grid, block, 0, stream>>>(Q, V, O);
}